// Round 1
// baseline (298.191 us; speedup 1.0000x reference)
//
#include <hip/hip_runtime.h>
#include <hip/hip_bf16.h>

// Conv2D 3x3 s1 p1: x[8,16,512,512] f32, w[16,144] f32 -> out[8,16,512,512] f32
//
// Implicit GEMM on bf16 MFMA (16x16x32), k = tap*16 + ci (K=144 pad 160).
// LDS tile: channels-last bf16 [18][34][16], 8B-slot swizzle slot=cg4^((pixel>>1)&2)
//   -> ds_read_b128 gives 8 contiguous channels (half = q ^ ((pixel>>2)&1)).
// R4 change (occupancy + staging ILP): tile TW 64->32 quarters LDS to 19.6 KB
//   -> 8 blocks/CU (32 waves, was 4 blocks/16 waves), __launch_bounds__(256,8)
//   pins VGPR<=64. Staging drops to 2.25 items/thread, issued as a 2-deep
//   pipeline (both items' dwordx4 in flight before first cvt). Weight-fragment
//   build moved after staging to cut peak register liveness.

#define IH 512
#define IW 512
#define CI 16
#define CO 16
#define TH 16
#define TW 32
#define LROWS (TH + 2)   // 18
#define LCOLS (TW + 2)   // 34
#define NITEMS (LROWS * (TW / 4) * 4)   // 576 interior staging items

typedef short short8  __attribute__((ext_vector_type(8)));
typedef short short4v __attribute__((ext_vector_type(4)));
typedef float f32x4   __attribute__((ext_vector_type(4)));

__device__ __forceinline__ short f32_to_bf16_bits(float v) {
    __hip_bfloat16 b = __float2bfloat16(v);   // RNE
    return __builtin_bit_cast(short, b);
}

struct ItemInfo {
    const float* src;
    int pb;      // pixel base = row*LCOLS + 1 + 4*wseg
    int ws;      // wseg
    int cg;      // channel group (4 ch)
    bool ok;     // row in bounds
};

__device__ __forceinline__ ItemInfo item_info(int i, int hbase, int wbase,
                                              const float* __restrict__ xn) {
    ItemInfo t;
    t.ws = i & 7;             // 8 wsegs of 4 cols
    t.cg = (i >> 3) & 3;
    const int row = i >> 5;   // 0..17
    const int gh  = hbase - 1 + row;
    t.ok  = (unsigned)gh < (unsigned)IH;
    t.src = xn + ((size_t)(t.cg * 4) * IH + gh) * IW + (wbase + 4 * t.ws);
    t.pb  = row * LCOLS + 1 + 4 * t.ws;
    return t;
}

__device__ __forceinline__ void item_load(const ItemInfo& t, f32x4 v[4]) {
    if (t.ok) {
#pragma unroll
        for (int jj = 0; jj < 4; ++jj)
            v[jj] = *(const f32x4*)(t.src + (size_t)jj * IH * IW);
    }
}

__device__ __forceinline__ void item_store(const ItemInfo& t, const f32x4 v[4],
                                           short* lds) {
    short4v pk[4];
    if (t.ok) {
#pragma unroll
        for (int j = 0; j < 4; ++j)
#pragma unroll
            for (int jj = 0; jj < 4; ++jj)
                pk[j][jj] = f32_to_bf16_bits(v[jj][j]);   // 4x4 transpose
    } else {
#pragma unroll
        for (int j = 0; j < 4; ++j) pk[j] = (short4v){0, 0, 0, 0};
    }
#pragma unroll
    for (int k = 0; k < 4; ++k) {
        const int j     = (k + t.ws) & 3;      // rotate: spread pixel phase -> banks
        const int pixel = t.pb + j;
        const int slot  = t.cg ^ ((pixel >> 1) & 2);
        *(short4v*)&lds[pixel * 16 + slot * 4] = pk[j];
    }
}

__global__ __launch_bounds__(256, 8)
void conv3x3_mfma(const float* __restrict__ x, const float* __restrict__ wgt,
                  float* __restrict__ out) {
    __shared__ short lds[LROWS * LCOLS * CI];   // 18*34*16*2 = 19584 B -> 8 blocks/CU

    const int tid  = threadIdx.x;
    const int wave = tid >> 6;
    const int lane = tid & 63;
    const int quad = lane >> 4;
    const int l15  = lane & 15;

    const int wbase = blockIdx.x * TW;
    const int hbase = blockIdx.y * TH;
    const int n     = blockIdx.z;

    const float* xn = x + (size_t)n * CI * IH * IW;

    // ---- interior staging: 576 items, 2-deep pipelined (2.25 items/thread) ----
    // item: 4x global_load_dwordx4 (ch cg*4..+3, w gw..gw+3) -> 4x4 transpose ->
    //       4x ds_write_b64 in wseg-rotated order
    ItemInfo t0 = item_info(tid,       hbase, wbase, xn);
    ItemInfo t1 = item_info(tid + 256, hbase, wbase, xn);
    f32x4 v0[4], v1[4], v2[4];
    item_load(t0, v0);
    item_load(t1, v1);
    const bool has2 = (tid + 512) < NITEMS;   // tid < 64
    ItemInfo t2 = item_info(has2 ? (tid + 512) : tid, hbase, wbase, xn);
    item_store(t0, v0, lds);
    if (has2) item_load(t2, v2);
    item_store(t1, v1, lds);
    if (has2) item_store(t2, v2, lds);

    // ---- halo cols c=0,33: 18 rows x 2 cols x 4 cgroups = 144 items ----
    if (tid < 144) {
        const int cg4  = tid & 3;
        const int col2 = (tid >> 2) & 1;
        const int row  = tid >> 3;              // 0..17
        const int c    = col2 ? (LCOLS - 1) : 0;
        const int gh   = hbase - 1 + row;
        const int gw   = wbase - 1 + c;         // wbase-1 or wbase+32
        const bool ok  = ((unsigned)gh < (unsigned)IH) && ((unsigned)gw < (unsigned)IW);
        short4v pk;
#pragma unroll
        for (int j = 0; j < 4; ++j) {
            const float v = ok ? xn[((size_t)(cg4 * 4 + j) * IH + gh) * IW + gw] : 0.0f;
            pk[j] = f32_to_bf16_bits(v);
        }
        const int pixel = row * LCOLS + c;
        const int slot  = cg4 ^ ((pixel >> 1) & 2);
        *(short4v*)&lds[pixel * 16 + slot * 4] = pk;
    }

    // ---- A fragments (after staging: lower peak VGPR liveness; L1-hot) ----
    // W[co=l15][k], k = f*32 + quad*8 + j; zero for k>=144
    short8 afrag[5];
#pragma unroll
    for (int f = 0; f < 5; ++f) {
#pragma unroll
        for (int j = 0; j < 8; ++j) {
            const int k = f * 32 + quad * 8 + j;
            float val = 0.0f;
            if (k < 144) {
                const int ci  = k & 15;
                const int tap = k >> 4;
                val = wgt[l15 * 144 + ci * 9 + tap];
            }
            afrag[f][j] = f32_to_bf16_bits(val);
        }
    }
    __syncthreads();

    // ---- per-f tap offsets (depend only on quad) ----
    const int q = quad & 1;
    int doff[5];
#pragma unroll
    for (int f = 0; f < 5; ++f) {
        const int tap = (f < 4) ? (f * 2 + (quad >> 1)) : 8;
        const int kh  = tap / 3;
        const int kw  = tap - kh * 3;
        doff[f] = kh * LCOLS + kw;
    }

    // ---- MFMA main: 4 h-rows x 2 w-segments per wave, 5 K-steps each ----
    f32x4 acc[4][2];
#pragma unroll
    for (int r = 0; r < 4; ++r)
#pragma unroll
        for (int c4 = 0; c4 < 2; ++c4)
            acc[r][c4] = (f32x4){0.f, 0.f, 0.f, 0.f};

#pragma unroll
    for (int r = 0; r < 4; ++r) {
        const int hl = wave * 4 + r;
#pragma unroll
        for (int c4 = 0; c4 < 2; ++c4) {
            const int wl    = c4 * 16 + l15;
            const int pbase = hl * LCOLS + wl;
#pragma unroll
            for (int f = 0; f < 5; ++f) {
                const int pixel = pbase + doff[f];
                const int half  = q ^ ((pixel >> 2) & 1);
                const short8 b  = *(const short8*)&lds[pixel * 16 + half * 8]; // ds_read_b128
                acc[r][c4] = __builtin_amdgcn_mfma_f32_16x16x32_bf16(afrag[f], b, acc[r][c4], 0, 0, 0);
            }
        }
    }

    // ---- store: C/D col = l15 = pixel, row = quad*4+reg = co ----
    float* on = out + (size_t)n * CO * IH * IW;
#pragma unroll
    for (int r = 0; r < 4; ++r) {
        const int gh = hbase + wave * 4 + r;
#pragma unroll
        for (int c4 = 0; c4 < 2; ++c4) {
            const int gw = wbase + c4 * 16 + l15;
#pragma unroll
            for (int reg = 0; reg < 4; ++reg) {
                const int co = quad * 4 + reg;
                on[((size_t)co * IH + gh) * IW + gw] = acc[r][c4][reg];
            }
        }
    }
}

extern "C" void kernel_launch(void* const* d_in, const int* in_sizes, int n_in,
                              void* d_out, int out_size, void* d_ws, size_t ws_size,
                              hipStream_t stream) {
    const float* x = (const float*)d_in[0];
    const float* w = (const float*)d_in[1];
    float* out     = (float*)d_out;

    dim3 grid(IW / TW, IH / TH, 8);   // 16 x 32 x 8 = 4096 blocks
    dim3 block(256);
    conv3x3_mfma<<<grid, block, 0, stream>>>(x, w, out);
}

// Round 2
// 290.246 us; speedup vs baseline: 1.0274x; 1.0274x over previous
//
#include <hip/hip_runtime.h>
#include <hip/hip_bf16.h>

// Conv2D 3x3 s1 p1: x[8,16,512,512] f32, w[16,144] f32 -> out[8,16,512,512] f32
//
// Implicit GEMM on bf16 MFMA (16x16x32), k = tap*16 + ci (K=144 pad 160).
// LDS tile: channels-last bf16 [18][34][16], 8B-slot swizzle slot=cg4^((pixel>>1)&2)
//   -> ds_read_b128 gives 8 contiguous channels (half = q ^ ((pixel>>2)&1)).
// R5 changes (fix R4's spills + cross-XCD halo refetch):
//   - __launch_bounds__(256,6): 85-VGPR budget (R4's (256,8)=64 cap spilled:
//     VGPR=32 + 24 MB scratch writes). 6 blocks/CU, LDS 19.6 KB permits it.
//   - staging pipeline capped at 2 live items (32 load VGPRs): load0,load1,
//     store0,load2->v0,store1,store2.
//   - XCD swizzle: 1D grid, image = bid&7 (one image per XCD under round-robin),
//     tile = bid>>3 with bx fastest -> x-neighbor tiles time-adjacent on same
//     XCD, boundary cache lines reused in L2 instead of refetched per-XCD.

#define IH 512
#define IW 512
#define CI 16
#define CO 16
#define TH 16
#define TW 32
#define LROWS (TH + 2)   // 18
#define LCOLS (TW + 2)   // 34
#define NITEMS (LROWS * (TW / 4) * 4)   // 576 interior staging items

typedef short short8  __attribute__((ext_vector_type(8)));
typedef short short4v __attribute__((ext_vector_type(4)));
typedef float f32x4   __attribute__((ext_vector_type(4)));

__device__ __forceinline__ short f32_to_bf16_bits(float v) {
    __hip_bfloat16 b = __float2bfloat16(v);   // RNE
    return __builtin_bit_cast(short, b);
}

struct ItemInfo {
    const float* src;
    int pb;      // pixel base = row*LCOLS + 1 + 4*wseg
    int ws;      // wseg
    int cg;      // channel group (4 ch)
    bool ok;     // row in bounds
};

__device__ __forceinline__ ItemInfo item_info(int i, int hbase, int wbase,
                                              const float* __restrict__ xn) {
    ItemInfo t;
    t.ws = i & 7;             // 8 wsegs of 4 cols
    t.cg = (i >> 3) & 3;
    const int row = i >> 5;   // 0..17
    const int gh  = hbase - 1 + row;
    t.ok  = (unsigned)gh < (unsigned)IH;
    t.src = xn + ((size_t)(t.cg * 4) * IH + gh) * IW + (wbase + 4 * t.ws);
    t.pb  = row * LCOLS + 1 + 4 * t.ws;
    return t;
}

__device__ __forceinline__ void item_load(const ItemInfo& t, f32x4 v[4]) {
    if (t.ok) {
#pragma unroll
        for (int jj = 0; jj < 4; ++jj)
            v[jj] = *(const f32x4*)(t.src + (size_t)jj * IH * IW);
    }
}

__device__ __forceinline__ void item_store(const ItemInfo& t, const f32x4 v[4],
                                           short* lds) {
    short4v pk[4];
    if (t.ok) {
#pragma unroll
        for (int j = 0; j < 4; ++j)
#pragma unroll
            for (int jj = 0; jj < 4; ++jj)
                pk[j][jj] = f32_to_bf16_bits(v[jj][j]);   // 4x4 transpose
    } else {
#pragma unroll
        for (int j = 0; j < 4; ++j) pk[j] = (short4v){0, 0, 0, 0};
    }
#pragma unroll
    for (int k = 0; k < 4; ++k) {
        const int j     = (k + t.ws) & 3;      // rotate: spread pixel phase -> banks
        const int pixel = t.pb + j;
        const int slot  = t.cg ^ ((pixel >> 1) & 2);
        *(short4v*)&lds[pixel * 16 + slot * 4] = pk[j];
    }
}

__global__ __launch_bounds__(256, 6)
void conv3x3_mfma(const float* __restrict__ x, const float* __restrict__ wgt,
                  float* __restrict__ out) {
    __shared__ short lds[LROWS * LCOLS * CI];   // 18*34*16*2 = 19584 B

    const int tid  = threadIdx.x;
    const int wave = tid >> 6;
    const int lane = tid & 63;
    const int quad = lane >> 4;
    const int l15  = lane & 15;

    // XCD swizzle: image fastest (1 image per XCD), then bx, then by
    const int bid   = blockIdx.x;
    const int n     = bid & 7;
    const int t     = bid >> 3;
    const int wbase = (t & 15) * TW;     // 16 tiles in x
    const int hbase = (t >> 4) * TH;     // 32 tiles in y

    const float* xn = x + (size_t)n * CI * IH * IW;

    // ---- interior staging: 576 items, 2-deep pipeline, <=2 items live ----
    // item: 4x global_load_dwordx4 (ch cg*4..+3, w gw..gw+3) -> 4x4 transpose ->
    //       4x ds_write_b64 in wseg-rotated order
    ItemInfo t0 = item_info(tid,       hbase, wbase, xn);
    ItemInfo t1 = item_info(tid + 256, hbase, wbase, xn);
    f32x4 v0[4], v1[4];
    item_load(t0, v0);
    item_load(t1, v1);
    item_store(t0, v0, lds);
    const bool has2 = tid < (NITEMS - 512);   // tid < 64
    ItemInfo t2 = item_info(has2 ? (tid + 512) : tid, hbase, wbase, xn);
    if (has2) item_load(t2, v0);              // reuse v0 registers
    item_store(t1, v1, lds);
    if (has2) item_store(t2, v0, lds);

    // ---- halo cols c=0,33: 18 rows x 2 cols x 4 cgroups = 144 items ----
    if (tid < 144) {
        const int cg4  = tid & 3;
        const int col2 = (tid >> 2) & 1;
        const int row  = tid >> 3;              // 0..17
        const int c    = col2 ? (LCOLS - 1) : 0;
        const int gh   = hbase - 1 + row;
        const int gw   = wbase - 1 + c;         // wbase-1 or wbase+32
        const bool ok  = ((unsigned)gh < (unsigned)IH) && ((unsigned)gw < (unsigned)IW);
        short4v pk;
#pragma unroll
        for (int j = 0; j < 4; ++j) {
            const float v = ok ? xn[((size_t)(cg4 * 4 + j) * IH + gh) * IW + gw] : 0.0f;
            pk[j] = f32_to_bf16_bits(v);
        }
        const int pixel = row * LCOLS + c;
        const int slot  = cg4 ^ ((pixel >> 1) & 2);
        *(short4v*)&lds[pixel * 16 + slot * 4] = pk;
    }

    // ---- A fragments (after staging: lower peak VGPR liveness; L2-hot) ----
    // W[co=l15][k], k = f*32 + quad*8 + j; zero for k>=144
    short8 afrag[5];
#pragma unroll
    for (int f = 0; f < 5; ++f) {
#pragma unroll
        for (int j = 0; j < 8; ++j) {
            const int k = f * 32 + quad * 8 + j;
            float val = 0.0f;
            if (k < 144) {
                const int ci  = k & 15;
                const int tap = k >> 4;
                val = wgt[l15 * 144 + ci * 9 + tap];
            }
            afrag[f][j] = f32_to_bf16_bits(val);
        }
    }
    __syncthreads();

    // ---- per-f tap offsets (depend only on quad) ----
    const int q = quad & 1;
    int doff[5];
#pragma unroll
    for (int f = 0; f < 5; ++f) {
        const int tap = (f < 4) ? (f * 2 + (quad >> 1)) : 8;
        const int kh  = tap / 3;
        const int kw  = tap - kh * 3;
        doff[f] = kh * LCOLS + kw;
    }

    // ---- MFMA main: 4 h-rows x 2 w-segments per wave, 5 K-steps each ----
    f32x4 acc[4][2];
#pragma unroll
    for (int r = 0; r < 4; ++r)
#pragma unroll
        for (int c4 = 0; c4 < 2; ++c4)
            acc[r][c4] = (f32x4){0.f, 0.f, 0.f, 0.f};

#pragma unroll
    for (int r = 0; r < 4; ++r) {
        const int hl = wave * 4 + r;
#pragma unroll
        for (int c4 = 0; c4 < 2; ++c4) {
            const int wl    = c4 * 16 + l15;
            const int pbase = hl * LCOLS + wl;
#pragma unroll
            for (int f = 0; f < 5; ++f) {
                const int pixel = pbase + doff[f];
                const int half  = q ^ ((pixel >> 2) & 1);
                const short8 b  = *(const short8*)&lds[pixel * 16 + half * 8]; // ds_read_b128
                acc[r][c4] = __builtin_amdgcn_mfma_f32_16x16x32_bf16(afrag[f], b, acc[r][c4], 0, 0, 0);
            }
        }
    }

    // ---- store: C/D col = l15 = pixel, row = quad*4+reg = co ----
    float* on = out + (size_t)n * CO * IH * IW;
#pragma unroll
    for (int r = 0; r < 4; ++r) {
        const int gh = hbase + wave * 4 + r;
#pragma unroll
        for (int c4 = 0; c4 < 2; ++c4) {
            const int gw = wbase + c4 * 16 + l15;
#pragma unroll
            for (int reg = 0; reg < 4; ++reg) {
                const int co = quad * 4 + reg;
                on[((size_t)co * IH + gh) * IW + gw] = acc[r][c4][reg];
            }
        }
    }
}

extern "C" void kernel_launch(void* const* d_in, const int* in_sizes, int n_in,
                              void* d_out, int out_size, void* d_ws, size_t ws_size,
                              hipStream_t stream) {
    const float* x = (const float*)d_in[0];
    const float* w = (const float*)d_in[1];
    float* out     = (float*)d_out;

    dim3 grid((IW / TW) * (IH / TH) * 8);   // 16*32*8 = 4096 blocks, 1D swizzled
    dim3 block(256);
    conv3x3_mfma<<<grid, block, 0, stream>>>(x, w, out);
}